// Round 7
// baseline (207.053 us; speedup 1.0000x reference)
//
#include <hip/hip_runtime.h>
#include <hip/hip_fp16.h>

// Problem constants (fixed by setup_inputs): B=4, N=50000, D=64, F=100000
constexpr int Bc = 4;
constexpr int Nc = 50000;
constexpr int Dc = 64;            // == wavefront size
constexpr int Fc = 100000;
constexpr int BN = Bc * Nc;       // 200000 vertices
constexpr int NFACES = Bc * Fc;   // 400000 faces
constexpr int NINC = NFACES * 3;  // 1.2M incidences
constexpr int CAP_E = 31;         // entries/vertex cap (deg ~ Poisson(6))

// ---------------- Tier A3: binned build + fused LDS bucket-gather ----------
// vh layout is batch-strided with a zeroed pad row per batch:
//   row(v) = v + (v/Nc);  pad row for batch b = b*(Nc+1)+Nc, addressable as
//   local id Nc (< 2^16). Sentinel entries gather exact zeros -> no masks.
//
// Round-7: binning = single-pass direct-atomic scatter (1 thread/face, 3
// global cursor atomics + 3 entry stores). Removes the 3-phase histogram/
// reserve machinery whose per-block NBINS-wide loops were pure overhead
// (256->512 block toggles moved total by only +/-5us). Zero LDS in the fill
// path; fused with convert as before. Gather (XCD-paired, 54us) untouched.
constexpr int BINV_SH = 7;                               // 128 verts/bin
constexpr int BINV    = 1 << BINV_SH;                    // 128
constexpr int NBINS   = (BN + BINV - 1) / BINV;          // 1563
constexpr int NBINS8  = ((NBINS + 7) / 8) * 8;           // 1568 (XCD-pad)
constexpr int BINCAP  = 1024;                            // mean 768, ~+9 sigma
constexpr int FILLB   = (NFACES + 255) / 256;            // 1563 fill blocks
constexpr int CONVB   = (BN * Dc / 8) / 256;             // 6250 fp16-convert blocks
constexpr unsigned int SENT = (unsigned)Nc | ((unsigned)Nc << 16);

// ws layout (bytes)
constexpr size_t A_VH    = 0;                            // __half[(BN+4)*64]
constexpr size_t A_ENT   = 25600512;                     // uint2[NBINS*BINCAP]
constexpr size_t A_BCUR  = A_ENT + (size_t)NBINS * BINCAP * 8;
constexpr size_t A3_NEED = A_BCUR + (size_t)NBINS * 32 * 4;

// Blocks [0,FILLB): direct-atomic entry placement (1 thread = 1 face).
// Blocks [FILLB, FILLB+CONVB): f32 -> fp16 convert into padded layout.
// Block FILLB+CONVB: zero the 4 pad rows.
__global__ __launch_bounds__(256) void bin_conv(
        const float* __restrict__ verts,
        const int*   __restrict__ faces,
        __half* __restrict__ vh,
        int*   __restrict__ bincur,       // NBINS cursors, padded 128B apart
        uint2* __restrict__ entries) {
    if ((int)blockIdx.x < FILLB) {
        int f = blockIdx.x * 256 + threadIdx.x;
        if (f >= NFACES) return;
        int base = (f / Fc) * Nc;
        unsigned int u0 = (unsigned int)faces[3*f+0];
        unsigned int u1 = (unsigned int)faces[3*f+1];
        unsigned int u2 = (unsigned int)faces[3*f+2];
        int g0 = (int)u0 + base, g1 = (int)u1 + base, g2 = (int)u2 + base;
        int b0 = g0 >> BINV_SH, b1 = g1 >> BINV_SH, b2 = g2 >> BINV_SH;
        int p0 = atomicAdd(&bincur[b0 * 32], 1);
        if (p0 < BINCAP) entries[(size_t)b0 * BINCAP + p0] = make_uint2((unsigned)g0, u1 | (u2 << 16));
        int p1 = atomicAdd(&bincur[b1 * 32], 1);
        if (p1 < BINCAP) entries[(size_t)b1 * BINCAP + p1] = make_uint2((unsigned)g1, u0 | (u2 << 16));
        int p2 = atomicAdd(&bincur[b2 * 32], 1);
        if (p2 < BINCAP) entries[(size_t)b2 * BINCAP + p2] = make_uint2((unsigned)g2, u0 | (u1 << 16));
    } else if ((int)blockIdx.x < FILLB + CONVB) {
        long idx = ((long)(blockIdx.x - FILLB) * 256 + threadIdx.x) * 8;
        int  v   = (int)(idx >> 6);
        int  b   = v / Nc;
        float4 a = *(const float4*)(verts + idx);
        float4 bb = *(const float4*)(verts + idx + 4);
        __half h[8];
        h[0] = __float2half(a.x);  h[1] = __float2half(a.y);
        h[2] = __float2half(a.z);  h[3] = __float2half(a.w);
        h[4] = __float2half(bb.x); h[5] = __float2half(bb.y);
        h[6] = __float2half(bb.z); h[7] = __float2half(bb.w);
        *(uint4*)(vh + idx + (long)b * 64) = *(const uint4*)h;
    } else {
        // zero the 4 pad rows (128 words)
        int t = threadIdx.x;
        if (t < 128) {
            int b = t >> 5, w = t & 31;
            ((unsigned int*)vh)[(long)(b * (Nc + 1) + Nc) * 32 + w] = 0u;
        }
    }
}

// TWO blocks per 128-vertex bin: both build the bin's records in LDS
// (count + 32 slots, slots prefilled with SENT so over-reads gather the
// zeroed pad row -> maskless); sub=0 gathers verts [0,64), sub=1 [64,128).
// Pair-to-XCD mapping: blockIdx groups of 16 = 8 bins x 2 subs with pair
// members 8 apart -> same XCD (round-robin %8) -> shared rows hit same L2.
// Wave = 2 vertices (halves); lane j = dims (2j,2j+1).
// Inner loop: step 4 packed entries -> 8 independent dword loads in flight.
__global__ __launch_bounds__(256) void bucket_gather(
        const __half* __restrict__ vh,
        const uint2*  __restrict__ entries,
        const int*    __restrict__ bincur,
        float* __restrict__ out) {
    __shared__ unsigned int scnt[BINV];
    __shared__ unsigned int sent[BINV * 32];   // 16 KB

    int d = blockIdx.x;
    int bin = (d >> 4) * 8 + (d & 7);
    int sub = (d >> 3) & 1;
    if (bin >= NBINS) return;
    int t = threadIdx.x;

    if (t < BINV) scnt[t] = 0;
    // vectorized SENT prefill (1024 uint4)
    {
        uint4* s4 = (uint4*)sent;
        uint4 sv = make_uint4(SENT, SENT, SENT, SENT);
        for (int i = t; i < BINV * 32 / 4; i += 256) s4[i] = sv;
    }
    __syncthreads();

    int total = bincur[bin * 32];
    if (total > BINCAP) total = BINCAP;
    const uint2* e = entries + (size_t)bin * BINCAP;
    int v0 = bin << BINV_SH;
    for (int i = t; i < total; i += 256) {
        uint2 en = e[i];
        int vl = (int)en.x - v0;                     // 0..127
        unsigned int r = atomicAdd(&scnt[vl], 1);
        if (r < (unsigned)CAP_E) sent[(vl << 5) + r] = en.y;   // slot 31 stays SENT
    }
    __syncthreads();

    int lane = t & 63, wv = t >> 6;
    int half = lane >> 5, j = lane & 31;
    const __half2* vh2 = (const __half2*)vh;
    int nrec = BN - v0; if (nrec > BINV) nrec = BINV;  // last bin: 64
    int vend = (sub + 1) << 6; if (vend > nrec) vend = nrec;   // this block's range

    for (int pair = (sub << 5) + wv; pair * 2 < vend; pair += 4) {
        int vl = pair * 2 + half;
        int v  = v0 + vl;
        int c  = (int)scnt[vl]; if (c > CAP_E) c = CAP_E;
        int cother = __shfl(c, lane ^ 32);
        int cmax = c > cother ? c : cother;          // wave-uniform-ish bound
        int b = v / Nc;
        int base2 = b * (Nc + 1);                    // padded-layout batch base

        float2 own = __half22float2(vh2[(v + b) * 32 + j]);

        const unsigned int* se = &sent[vl << 5];
        float accx = 0.f, accy = 0.f;
        for (int i = 0; i < cmax; i += 4) {
            unsigned int p0 = se[i];
            unsigned int p1 = se[i + 1];
            unsigned int p2 = se[i + 2];
            unsigned int p3 = se[i + 3];
            int r0 = (base2 + (int)(p0 & 0xFFFFu)) * 32 + j;
            int r1 = (base2 + (int)(p0 >> 16))     * 32 + j;
            int r2 = (base2 + (int)(p1 & 0xFFFFu)) * 32 + j;
            int r3 = (base2 + (int)(p1 >> 16))     * 32 + j;
            int r4 = (base2 + (int)(p2 & 0xFFFFu)) * 32 + j;
            int r5 = (base2 + (int)(p2 >> 16))     * 32 + j;
            int r6 = (base2 + (int)(p3 & 0xFFFFu)) * 32 + j;
            int r7 = (base2 + (int)(p3 >> 16))     * 32 + j;
            float2 f0 = __half22float2(vh2[r0]);
            float2 f1 = __half22float2(vh2[r1]);
            float2 f2 = __half22float2(vh2[r2]);
            float2 f3 = __half22float2(vh2[r3]);
            float2 f4 = __half22float2(vh2[r4]);
            float2 f5 = __half22float2(vh2[r5]);
            float2 f6 = __half22float2(vh2[r6]);
            float2 f7 = __half22float2(vh2[r7]);
            accx += (f0.x + f1.x) + (f2.x + f3.x) + (f4.x + f5.x) + (f6.x + f7.x);
            accy += (f0.y + f1.y) + (f2.y + f3.y) + (f4.y + f5.y) + (f6.y + f7.y);
        }

        float deg = 2.0f * (float)c;
        float den = deg + 1e-12f;
        float2 r;
        r.x = (deg * own.x - accx) / den;
        r.y = (deg * own.y - accy) / den;
        ((float2*)out)[(long)v * 32 + j] = r;
    }
}

// ---------------- Tier B (round-4 proven): direct record fill + gather2 ------
constexpr size_t B_VH   = 0;
constexpr size_t B_REC  = 25600000;
constexpr size_t B_NEED = 51200000;

__global__ __launch_bounds__(256) void conv_fill(
        const float* __restrict__ verts,
        const int*   __restrict__ faces,
        __half* __restrict__ vh,
        unsigned int* __restrict__ rec) {
    if ((int)blockIdx.x < FILLB) {
        int f = blockIdx.x * 256 + threadIdx.x;
        if (f >= NFACES) return;
        int base = (f / Fc) * Nc;
        unsigned int u0 = (unsigned int)faces[3*f+0];
        unsigned int u1 = (unsigned int)faces[3*f+1];
        unsigned int u2 = (unsigned int)faces[3*f+2];
        unsigned int* r0 = rec + (long)((int)u0 + base) * 32;
        unsigned int* r1 = rec + (long)((int)u1 + base) * 32;
        unsigned int* r2 = rec + (long)((int)u2 + base) * 32;
        int s0 = atomicAdd((int*)r0, 1);
        if (s0 < CAP_E) r0[1 + s0] = u1 | (u2 << 16);
        int s1 = atomicAdd((int*)r1, 1);
        if (s1 < CAP_E) r1[1 + s1] = u0 | (u2 << 16);
        int s2 = atomicAdd((int*)r2, 1);
        if (s2 < CAP_E) r2[1 + s2] = u0 | (u1 << 16);
    } else {
        long idx = ((long)(blockIdx.x - FILLB) * 256 + threadIdx.x) * 8;
        float4 a = *(const float4*)(verts + idx);
        float4 b = *(const float4*)(verts + idx + 4);
        __half h[8];
        h[0] = __float2half(a.x); h[1] = __float2half(a.y);
        h[2] = __float2half(a.z); h[3] = __float2half(a.w);
        h[4] = __float2half(b.x); h[5] = __float2half(b.y);
        h[6] = __float2half(b.z); h[7] = __float2half(b.w);
        *(uint4*)(vh + idx) = *(const uint4*)h;
    }
}

__global__ __launch_bounds__(256) void gather2(
        const float*  __restrict__ verts,
        const __half* __restrict__ vh,
        const unsigned int* __restrict__ rec,
        float* __restrict__ out) {
    int gtid = blockIdx.x * 256 + threadIdx.x;
    int w    = gtid >> 6;
    int lane = threadIdx.x & 63;
    int half = lane >> 5;
    int j    = lane & 31;
    int v    = 2 * w + half;
    int h32  = half << 5;

    unsigned int rw = rec[(long)w * 64 + lane];
    int c = __shfl((int)rw, h32);
    if (c > CAP_E) c = CAP_E;
    int cother = __shfl(c, lane ^ 32);
    int cmax = c > cother ? c : cother;

    int base = (v / Nc) * Nc;
    const __half2* vh2 = (const __half2*)vh;
    float2 own = ((const float2*)verts)[(long)v * 32 + j];

    float accx = 0.f, accy = 0.f;
    for (int i = 0; i < cmax; i += 2) {
        unsigned int p0 = (unsigned int)__shfl((int)rw, h32 + 1 + i);
        unsigned int p1 = (unsigned int)__shfl((int)rw, h32 + 2 + i);
        float m0 = (i < c) ? 1.f : 0.f;
        float m1 = (i + 1 < c) ? 1.f : 0.f;
        unsigned int q0 = (i < c) ? p0 : 0u;
        unsigned int q1 = (i + 1 < c) ? p1 : 0u;
        long r0 = (long)(base + (int)(q0 & 0xFFFFu)) * 32 + j;
        long r1 = (long)(base + (int)(q0 >> 16))     * 32 + j;
        long r2 = (long)(base + (int)(q1 & 0xFFFFu)) * 32 + j;
        long r3 = (long)(base + (int)(q1 >> 16))     * 32 + j;
        float2 f0 = __half22float2(vh2[r0]);
        float2 f1 = __half22float2(vh2[r1]);
        float2 f2 = __half22float2(vh2[r2]);
        float2 f3 = __half22float2(vh2[r3]);
        accx += m0 * (f0.x + f1.x) + m1 * (f2.x + f3.x);
        accy += m0 * (f0.y + f1.y) + m1 * (f2.y + f3.y);
    }

    float deg = 2.0f * (float)c;
    float den = deg + 1e-12f;
    float2 r;
    r.x = (deg * own.x - accx) / den;
    r.y = (deg * own.y - accy) / den;
    ((float2*)out)[(long)v * 32 + j] = r;
}

// ---------------- Tier C: CSR f32 fallback (round-2 proven) ----------------
constexpr int SCAN_ELEMS = 1024;
constexpr int NSCAN = (BN + SCAN_ELEMS - 1) / SCAN_ELEMS;
constexpr size_t WS_COUNTS  = 0;
constexpr size_t WS_OFFSETS = 800000;
constexpr size_t WS_CURSORS = 1600000;
constexpr size_t WS_BSUMS   = 2400000;
constexpr size_t WS_BBASE   = 2401024;
constexpr size_t WS_ENTRIES = 2402048;
constexpr size_t WS_NEEDED  = WS_ENTRIES + (size_t)NINC * 8;

__global__ __launch_bounds__(256) void count_kernel(
        const int* __restrict__ faces, int* __restrict__ counts) {
    int f = blockIdx.x * blockDim.x + threadIdx.x;
    if (f >= NFACES) return;
    int base = (f / Fc) * Nc;
    atomicAdd(&counts[faces[3*f+0] + base], 1);
    atomicAdd(&counts[faces[3*f+1] + base], 1);
    atomicAdd(&counts[faces[3*f+2] + base], 1);
}

__global__ __launch_bounds__(256) void scanA(
        const int* __restrict__ counts, int* __restrict__ bsums) {
    __shared__ int s[256];
    int t = threadIdx.x, b = blockIdx.x;
    int idx = b * SCAN_ELEMS + t * 4;
    int v = 0;
    if (idx + 4 <= BN) {
        int4 c = *(const int4*)(counts + idx);
        v = c.x + c.y + c.z + c.w;
    }
    s[t] = v; __syncthreads();
    for (int o = 128; o > 0; o >>= 1) {
        if (t < o) s[t] += s[t + o];
        __syncthreads();
    }
    if (t == 0) bsums[b] = s[0];
}

__global__ __launch_bounds__(256) void scanB(
        const int* __restrict__ bsums, int* __restrict__ bbase) {
    __shared__ int s[256];
    int t = threadIdx.x;
    int x = (t < NSCAN) ? bsums[t] : 0;
    s[t] = x; __syncthreads();
    for (int o = 1; o < 256; o <<= 1) {
        int v = (t >= o) ? s[t - o] : 0;
        __syncthreads();
        s[t] += v;
        __syncthreads();
    }
    bbase[t] = s[t] - x;
}

__global__ __launch_bounds__(256) void scanC(
        const int* __restrict__ counts, const int* __restrict__ bbase,
        int* __restrict__ offsets) {
    __shared__ int s[256];
    int t = threadIdx.x, b = blockIdx.x;
    int idx = b * SCAN_ELEMS + t * 4;
    int4 c = make_int4(0, 0, 0, 0);
    bool ok = (idx + 4 <= BN);
    if (ok) c = *(const int4*)(counts + idx);
    int tsum = c.x + c.y + c.z + c.w;
    s[t] = tsum; __syncthreads();
    for (int o = 1; o < 256; o <<= 1) {
        int v = (t >= o) ? s[t - o] : 0;
        __syncthreads();
        s[t] += v;
        __syncthreads();
    }
    int tbase = bbase[b] + s[t] - tsum;
    if (ok) {
        int4 o4;
        o4.x = tbase;
        o4.y = tbase + c.x;
        o4.z = tbase + c.x + c.y;
        o4.w = tbase + c.x + c.y + c.z;
        *(int4*)(offsets + idx) = o4;
    }
}

__global__ __launch_bounds__(256) void fill_kernel(
        const int* __restrict__ faces,
        const int* __restrict__ offsets,
        int* __restrict__ cursors,
        int2* __restrict__ entries) {
    int f = blockIdx.x * blockDim.x + threadIdx.x;
    if (f >= NFACES) return;
    int base = (f / Fc) * Nc;
    int v0 = faces[3*f+0] + base;
    int v1 = faces[3*f+1] + base;
    int v2 = faces[3*f+2] + base;
    int p0 = offsets[v0] + atomicAdd(&cursors[v0], 1);
    entries[p0] = make_int2(v1, v2);
    int p1 = offsets[v1] + atomicAdd(&cursors[v1], 1);
    entries[p1] = make_int2(v0, v2);
    int p2 = offsets[v2] + atomicAdd(&cursors[v2], 1);
    entries[p2] = make_int2(v0, v1);
}

__global__ __launch_bounds__(256) void gather_kernel(
        const float* __restrict__ verts,
        const int* __restrict__ counts,
        const int* __restrict__ offsets,
        const int2* __restrict__ entries,
        float* __restrict__ out) {
    int v    = (int)((blockIdx.x * blockDim.x + threadIdx.x) >> 6);
    int lane = threadIdx.x & 63;
    if (v >= BN) return;
    int c = counts[v];
    const int2* e = entries + offsets[v];
    float acc = 0.f;
    int i = 0;
    for (; i + 2 <= c; i += 2) {
        int2 a = e[i];
        int2 b = e[i + 1];
        acc += verts[(long)a.x * Dc + lane] + verts[(long)a.y * Dc + lane]
             + verts[(long)b.x * Dc + lane] + verts[(long)b.y * Dc + lane];
    }
    if (i < c) {
        int2 a = e[i];
        acc += verts[(long)a.x * Dc + lane] + verts[(long)a.y * Dc + lane];
    }
    float deg = 2.0f * (float)c;
    float own = verts[(long)v * Dc + lane];
    out[(long)v * Dc + lane] = (deg * own - acc) / (deg + 1e-12f);
}

extern "C" void kernel_launch(void* const* d_in, const int* in_sizes, int n_in,
                              void* d_out, int out_size, void* d_ws, size_t ws_size,
                              hipStream_t stream) {
    const float* verts = (const float*)d_in[0];
    const int*   faces = (const int*)d_in[1];   // int32 (JAX x64 disabled)
    float* out = (float*)d_out;
    char*  ws  = (char*)d_ws;

    if (ws_size >= A3_NEED) {
        // ---- Tier A3: binned build + fused LDS bucket-gather ----
        __half*       vh      = (__half*)(ws + A_VH);
        uint2*        entries = (uint2*)(ws + A_ENT);
        int*          bincur  = (int*)(ws + A_BCUR);

        hipMemsetAsync(bincur, 0, (size_t)NBINS * 32 * sizeof(int), stream);
        bin_conv<<<FILLB + CONVB + 1, 256, 0, stream>>>(verts, faces, vh, bincur, entries);
        bucket_gather<<<NBINS8 * 2, 256, 0, stream>>>(vh, entries, bincur, out);
    } else if (ws_size >= B_NEED) {
        // ---- Tier B: round-4 direct record fill ----
        __half*       vh  = (__half*)(ws + B_VH);
        unsigned int* rec = (unsigned int*)(ws + B_REC);
        hipMemsetAsync(rec, 0, (size_t)BN * 32 * sizeof(unsigned int), stream);
        conv_fill<<<FILLB + CONVB, 256, 0, stream>>>(verts, faces, vh, rec);
        gather2<<<BN * 32 / 256, 256, 0, stream>>>(verts, vh, rec, out);
    } else if (ws_size >= WS_NEEDED) {
        // ---- Tier C: CSR f32 ----
        int*  counts  = (int*)(ws + WS_COUNTS);
        int*  offsets = (int*)(ws + WS_OFFSETS);
        int*  cursors = (int*)(ws + WS_CURSORS);
        int*  bsums   = (int*)(ws + WS_BSUMS);
        int*  bbase   = (int*)(ws + WS_BBASE);
        int2* entries = (int2*)(ws + WS_ENTRIES);

        hipMemsetAsync(counts,  0, (size_t)BN * sizeof(int), stream);
        hipMemsetAsync(cursors, 0, (size_t)BN * sizeof(int), stream);
        int fb = (NFACES + 255) / 256;
        count_kernel<<<fb, 256, 0, stream>>>(faces, counts);
        scanA<<<NSCAN, 256, 0, stream>>>(counts, bsums);
        scanB<<<1, 256, 0, stream>>>(bsums, bbase);
        scanC<<<NSCAN, 256, 0, stream>>>(counts, bbase, offsets);
        fill_kernel<<<fb, 256, 0, stream>>>(faces, offsets, cursors, entries);
        int gb = (BN * 64 + 255) / 256;
        gather_kernel<<<gb, 256, 0, stream>>>(verts, counts, offsets, entries, out);
    }
}

// Round 8
// 157.666 us; speedup vs baseline: 1.3132x; 1.3132x over previous
//
#include <hip/hip_runtime.h>
#include <hip/hip_fp16.h>

// Problem constants (fixed by setup_inputs): B=4, N=50000, D=64, F=100000
constexpr int Bc = 4;
constexpr int Nc = 50000;
constexpr int Dc = 64;            // == wavefront size
constexpr int Fc = 100000;
constexpr int BN = Bc * Nc;       // 200000 vertices
constexpr int NFACES = Bc * Fc;   // 400000 faces
constexpr int NINC = NFACES * 3;  // 1.2M incidences
constexpr int CAP_E = 31;         // entries/vertex cap (deg ~ Poisson(6))

// ---------------- Tier A3: binned build + fused LDS bucket-gather ----------
// vh layout is batch-strided with a zeroed pad row per batch:
//   row(v) = v + (v/Nc);  pad row for batch b = b*(Nc+1)+Nc, addressable as
//   local id Nc (< 2^16). Sentinel entries gather exact zeros -> no masks.
//
// Round-8: revert binning to the proven 3-phase LDS-aggregated build with
// 256 blocks (round-7's direct-atomic scatter was 88us: 770 serialized L2
// atomics/cursor, VALU 1% — LDS aggregation IS the win; 256 beat 512 in the
// A/B). Keep XCD-paired gather; NEW: gather inner loop step 4 -> 8 entries
// (16 outstanding dword loads/wave, Little's law on the latency-bound path).
constexpr int BINV_SH = 7;                               // 128 verts/bin
constexpr int BINV    = 1 << BINV_SH;                    // 128
constexpr int NBINS   = (BN + BINV - 1) / BINV;          // 1563
constexpr int NBINS8  = ((NBINS + 7) / 8) * 8;           // 1568 (XCD-pad)
constexpr int BINCAP  = 1024;                            // mean 768, ~+9 sigma
constexpr int BINB    = 256;                             // binning blocks (R4 best)
constexpr int FPB     = (NFACES + BINB - 1) / BINB;      // 1563 faces/block
constexpr int CONVB   = (BN * Dc / 8) / 256;             // 6250 fp16-convert blocks
constexpr unsigned int SENT = (unsigned)Nc | ((unsigned)Nc << 16);

// ws layout (bytes)
constexpr size_t A_VH    = 0;                            // __half[(BN+4)*64]
constexpr size_t A_ENT   = 25600512;                     // uint2[NBINS*BINCAP]
constexpr size_t A_BCUR  = A_ENT + (size_t)NBINS * BINCAP * 8;
constexpr size_t A3_NEED = A_BCUR + (size_t)NBINS * 32 * 4;

// Blocks [0,BINB): partition incidences into per-bin segments (3-phase).
// Blocks [BINB, BINB+CONVB): f32 -> fp16 convert into padded layout.
// Block BINB+CONVB: zero the 4 pad rows.
__global__ __launch_bounds__(256) void bin_conv(
        const float* __restrict__ verts,
        const int*   __restrict__ faces,
        __half* __restrict__ vh,
        int*   __restrict__ bincur,       // NBINS cursors, padded 128B apart
        uint2* __restrict__ entries) {
    __shared__ unsigned int sfaces[FPB * 3];   // 18.8 KB
    __shared__ int scnt[NBINS];                // 6.3 KB
    __shared__ int sbase[NBINS];               // 6.3 KB

    if ((int)blockIdx.x < BINB) {
        int blk = blockIdx.x, t = threadIdx.x;
        int f0g = blk * FPB;
        int nf  = NFACES - f0g; if (nf > FPB) nf = FPB;
        if (nf <= 0) return;

        for (int i = t; i < nf * 3; i += 256) sfaces[i] = (unsigned int)faces[f0g * 3 + i];
        for (int i = t; i < NBINS; i += 256) scnt[i] = 0;
        __syncthreads();

        // phase 1: per-bin histogram (LDS atomics)
        for (int f = t; f < nf; f += 256) {
            int base = ((f0g + f) / Fc) * Nc;
            int g0 = (int)sfaces[3*f+0] + base;
            int g1 = (int)sfaces[3*f+1] + base;
            int g2 = (int)sfaces[3*f+2] + base;
            atomicAdd(&scnt[g0 >> BINV_SH], 1);
            atomicAdd(&scnt[g1 >> BINV_SH], 1);
            atomicAdd(&scnt[g2 >> BINV_SH], 1);
        }
        __syncthreads();

        // reserve contiguous segments (1 global atomic per touched bin)
        for (int i = t; i < NBINS; i += 256) {
            int c = scnt[i];
            sbase[i] = (c > 0) ? atomicAdd(&bincur[i * 32], c) : 0;
            scnt[i] = 0;
        }
        __syncthreads();

        // phase 2: place entries at reserved positions
        for (int f = t; f < nf; f += 256) {
            unsigned int u0 = sfaces[3*f+0];
            unsigned int u1 = sfaces[3*f+1];
            unsigned int u2 = sfaces[3*f+2];
            int base = ((f0g + f) / Fc) * Nc;
            int g0 = (int)u0 + base, g1 = (int)u1 + base, g2 = (int)u2 + base;
            int b0 = g0 >> BINV_SH, b1 = g1 >> BINV_SH, b2 = g2 >> BINV_SH;
            int p0 = sbase[b0] + atomicAdd(&scnt[b0], 1);
            if (p0 < BINCAP) entries[(size_t)b0 * BINCAP + p0] = make_uint2((unsigned)g0, u1 | (u2 << 16));
            int p1 = sbase[b1] + atomicAdd(&scnt[b1], 1);
            if (p1 < BINCAP) entries[(size_t)b1 * BINCAP + p1] = make_uint2((unsigned)g1, u0 | (u2 << 16));
            int p2 = sbase[b2] + atomicAdd(&scnt[b2], 1);
            if (p2 < BINCAP) entries[(size_t)b2 * BINCAP + p2] = make_uint2((unsigned)g2, u0 | (u1 << 16));
        }
    } else if ((int)blockIdx.x < BINB + CONVB) {
        long idx = ((long)(blockIdx.x - BINB) * 256 + threadIdx.x) * 8;
        int  v   = (int)(idx >> 6);
        int  b   = v / Nc;
        float4 a = *(const float4*)(verts + idx);
        float4 bb = *(const float4*)(verts + idx + 4);
        __half h[8];
        h[0] = __float2half(a.x);  h[1] = __float2half(a.y);
        h[2] = __float2half(a.z);  h[3] = __float2half(a.w);
        h[4] = __float2half(bb.x); h[5] = __float2half(bb.y);
        h[6] = __float2half(bb.z); h[7] = __float2half(bb.w);
        *(uint4*)(vh + idx + (long)b * 64) = *(const uint4*)h;
    } else {
        // zero the 4 pad rows (128 words)
        int t = threadIdx.x;
        if (t < 128) {
            int b = t >> 5, w = t & 31;
            ((unsigned int*)vh)[(long)(b * (Nc + 1) + Nc) * 32 + w] = 0u;
        }
    }
}

// TWO blocks per 128-vertex bin: both build the bin's records in LDS
// (count + 32 slots, slots prefilled with SENT so over-reads gather the
// zeroed pad row -> maskless); sub=0 gathers verts [0,64), sub=1 [64,128).
// Pair-to-XCD mapping: blockIdx groups of 16 = 8 bins x 2 subs with pair
// members 8 apart -> same XCD (round-robin %8) -> shared rows hit same L2.
// Wave = 2 vertices (halves); lane j = dims (2j,2j+1).
// Inner loop: step 8 packed entries -> 16 independent dword loads in flight.
__global__ __launch_bounds__(256) void bucket_gather(
        const __half* __restrict__ vh,
        const uint2*  __restrict__ entries,
        const int*    __restrict__ bincur,
        float* __restrict__ out) {
    __shared__ unsigned int scnt[BINV];
    __shared__ unsigned int sent[BINV * 32];   // 16 KB

    int d = blockIdx.x;
    int bin = (d >> 4) * 8 + (d & 7);
    int sub = (d >> 3) & 1;
    if (bin >= NBINS) return;
    int t = threadIdx.x;

    if (t < BINV) scnt[t] = 0;
    // vectorized SENT prefill (1024 uint4)
    {
        uint4* s4 = (uint4*)sent;
        uint4 sv = make_uint4(SENT, SENT, SENT, SENT);
        for (int i = t; i < BINV * 32 / 4; i += 256) s4[i] = sv;
    }
    __syncthreads();

    int total = bincur[bin * 32];
    if (total > BINCAP) total = BINCAP;
    const uint2* e = entries + (size_t)bin * BINCAP;
    int v0 = bin << BINV_SH;
    for (int i = t; i < total; i += 256) {
        uint2 en = e[i];
        int vl = (int)en.x - v0;                     // 0..127
        unsigned int r = atomicAdd(&scnt[vl], 1);
        if (r < (unsigned)CAP_E) sent[(vl << 5) + r] = en.y;   // slot 31 stays SENT
    }
    __syncthreads();

    int lane = t & 63, wv = t >> 6;
    int half = lane >> 5, j = lane & 31;
    const __half2* vh2 = (const __half2*)vh;
    int nrec = BN - v0; if (nrec > BINV) nrec = BINV;  // last bin: 64
    int vend = (sub + 1) << 6; if (vend > nrec) vend = nrec;   // this block's range

    for (int pair = (sub << 5) + wv; pair * 2 < vend; pair += 4) {
        int vl = pair * 2 + half;
        int v  = v0 + vl;
        int c  = (int)scnt[vl]; if (c > CAP_E) c = CAP_E;
        int cother = __shfl(c, lane ^ 32);
        int cmax = c > cother ? c : cother;          // wave-uniform-ish bound
        int b = v / Nc;
        int base2 = b * (Nc + 1);                    // padded-layout batch base

        float2 own = __half22float2(vh2[(v + b) * 32 + j]);

        const unsigned int* se = &sent[vl << 5];
        float accx = 0.f, accy = 0.f;
        for (int i = 0; i < cmax; i += 8) {
            unsigned int p0 = se[i];
            unsigned int p1 = se[i + 1];
            unsigned int p2 = se[i + 2];
            unsigned int p3 = se[i + 3];
            unsigned int p4 = se[i + 4];
            unsigned int p5 = se[i + 5];
            unsigned int p6 = se[i + 6];
            unsigned int p7 = se[i + 7];
            int r0  = (base2 + (int)(p0 & 0xFFFFu)) * 32 + j;
            int r1  = (base2 + (int)(p0 >> 16))     * 32 + j;
            int r2  = (base2 + (int)(p1 & 0xFFFFu)) * 32 + j;
            int r3  = (base2 + (int)(p1 >> 16))     * 32 + j;
            int r4  = (base2 + (int)(p2 & 0xFFFFu)) * 32 + j;
            int r5  = (base2 + (int)(p2 >> 16))     * 32 + j;
            int r6  = (base2 + (int)(p3 & 0xFFFFu)) * 32 + j;
            int r7  = (base2 + (int)(p3 >> 16))     * 32 + j;
            int r8  = (base2 + (int)(p4 & 0xFFFFu)) * 32 + j;
            int r9  = (base2 + (int)(p4 >> 16))     * 32 + j;
            int r10 = (base2 + (int)(p5 & 0xFFFFu)) * 32 + j;
            int r11 = (base2 + (int)(p5 >> 16))     * 32 + j;
            int r12 = (base2 + (int)(p6 & 0xFFFFu)) * 32 + j;
            int r13 = (base2 + (int)(p6 >> 16))     * 32 + j;
            int r14 = (base2 + (int)(p7 & 0xFFFFu)) * 32 + j;
            int r15 = (base2 + (int)(p7 >> 16))     * 32 + j;
            float2 f0  = __half22float2(vh2[r0]);
            float2 f1  = __half22float2(vh2[r1]);
            float2 f2  = __half22float2(vh2[r2]);
            float2 f3  = __half22float2(vh2[r3]);
            float2 f4  = __half22float2(vh2[r4]);
            float2 f5  = __half22float2(vh2[r5]);
            float2 f6  = __half22float2(vh2[r6]);
            float2 f7  = __half22float2(vh2[r7]);
            float2 f8  = __half22float2(vh2[r8]);
            float2 f9  = __half22float2(vh2[r9]);
            float2 f10 = __half22float2(vh2[r10]);
            float2 f11 = __half22float2(vh2[r11]);
            float2 f12 = __half22float2(vh2[r12]);
            float2 f13 = __half22float2(vh2[r13]);
            float2 f14 = __half22float2(vh2[r14]);
            float2 f15 = __half22float2(vh2[r15]);
            accx += ((f0.x + f1.x) + (f2.x + f3.x)) + ((f4.x + f5.x) + (f6.x + f7.x))
                  + ((f8.x + f9.x) + (f10.x + f11.x)) + ((f12.x + f13.x) + (f14.x + f15.x));
            accy += ((f0.y + f1.y) + (f2.y + f3.y)) + ((f4.y + f5.y) + (f6.y + f7.y))
                  + ((f8.y + f9.y) + (f10.y + f11.y)) + ((f12.y + f13.y) + (f14.y + f15.y));
        }

        float deg = 2.0f * (float)c;
        float den = deg + 1e-12f;
        float2 r;
        r.x = (deg * own.x - accx) / den;
        r.y = (deg * own.y - accy) / den;
        ((float2*)out)[(long)v * 32 + j] = r;
    }
}

// ---------------- Tier B (round-4 proven): direct record fill + gather2 ------
constexpr size_t B_VH   = 0;
constexpr size_t B_REC  = 25600000;
constexpr size_t B_NEED = 51200000;
constexpr int FILLB = (NFACES + 255) / 256;

__global__ __launch_bounds__(256) void conv_fill(
        const float* __restrict__ verts,
        const int*   __restrict__ faces,
        __half* __restrict__ vh,
        unsigned int* __restrict__ rec) {
    if ((int)blockIdx.x < FILLB) {
        int f = blockIdx.x * 256 + threadIdx.x;
        if (f >= NFACES) return;
        int base = (f / Fc) * Nc;
        unsigned int u0 = (unsigned int)faces[3*f+0];
        unsigned int u1 = (unsigned int)faces[3*f+1];
        unsigned int u2 = (unsigned int)faces[3*f+2];
        unsigned int* r0 = rec + (long)((int)u0 + base) * 32;
        unsigned int* r1 = rec + (long)((int)u1 + base) * 32;
        unsigned int* r2 = rec + (long)((int)u2 + base) * 32;
        int s0 = atomicAdd((int*)r0, 1);
        if (s0 < CAP_E) r0[1 + s0] = u1 | (u2 << 16);
        int s1 = atomicAdd((int*)r1, 1);
        if (s1 < CAP_E) r1[1 + s1] = u0 | (u2 << 16);
        int s2 = atomicAdd((int*)r2, 1);
        if (s2 < CAP_E) r2[1 + s2] = u0 | (u1 << 16);
    } else {
        long idx = ((long)(blockIdx.x - FILLB) * 256 + threadIdx.x) * 8;
        float4 a = *(const float4*)(verts + idx);
        float4 b = *(const float4*)(verts + idx + 4);
        __half h[8];
        h[0] = __float2half(a.x); h[1] = __float2half(a.y);
        h[2] = __float2half(a.z); h[3] = __float2half(a.w);
        h[4] = __float2half(b.x); h[5] = __float2half(b.y);
        h[6] = __float2half(b.z); h[7] = __float2half(b.w);
        *(uint4*)(vh + idx) = *(const uint4*)h;
    }
}

__global__ __launch_bounds__(256) void gather2(
        const float*  __restrict__ verts,
        const __half* __restrict__ vh,
        const unsigned int* __restrict__ rec,
        float* __restrict__ out) {
    int gtid = blockIdx.x * 256 + threadIdx.x;
    int w    = gtid >> 6;
    int lane = threadIdx.x & 63;
    int half = lane >> 5;
    int j    = lane & 31;
    int v    = 2 * w + half;
    int h32  = half << 5;

    unsigned int rw = rec[(long)w * 64 + lane];
    int c = __shfl((int)rw, h32);
    if (c > CAP_E) c = CAP_E;
    int cother = __shfl(c, lane ^ 32);
    int cmax = c > cother ? c : cother;

    int base = (v / Nc) * Nc;
    const __half2* vh2 = (const __half2*)vh;
    float2 own = ((const float2*)verts)[(long)v * 32 + j];

    float accx = 0.f, accy = 0.f;
    for (int i = 0; i < cmax; i += 2) {
        unsigned int p0 = (unsigned int)__shfl((int)rw, h32 + 1 + i);
        unsigned int p1 = (unsigned int)__shfl((int)rw, h32 + 2 + i);
        float m0 = (i < c) ? 1.f : 0.f;
        float m1 = (i + 1 < c) ? 1.f : 0.f;
        unsigned int q0 = (i < c) ? p0 : 0u;
        unsigned int q1 = (i + 1 < c) ? p1 : 0u;
        long r0 = (long)(base + (int)(q0 & 0xFFFFu)) * 32 + j;
        long r1 = (long)(base + (int)(q0 >> 16))     * 32 + j;
        long r2 = (long)(base + (int)(q1 & 0xFFFFu)) * 32 + j;
        long r3 = (long)(base + (int)(q1 >> 16))     * 32 + j;
        float2 f0 = __half22float2(vh2[r0]);
        float2 f1 = __half22float2(vh2[r1]);
        float2 f2 = __half22float2(vh2[r2]);
        float2 f3 = __half22float2(vh2[r3]);
        accx += m0 * (f0.x + f1.x) + m1 * (f2.x + f3.x);
        accy += m0 * (f0.y + f1.y) + m1 * (f2.y + f3.y);
    }

    float deg = 2.0f * (float)c;
    float den = deg + 1e-12f;
    float2 r;
    r.x = (deg * own.x - accx) / den;
    r.y = (deg * own.y - accy) / den;
    ((float2*)out)[(long)v * 32 + j] = r;
}

// ---------------- Tier C: CSR f32 fallback (round-2 proven) ----------------
constexpr int SCAN_ELEMS = 1024;
constexpr int NSCAN = (BN + SCAN_ELEMS - 1) / SCAN_ELEMS;
constexpr size_t WS_COUNTS  = 0;
constexpr size_t WS_OFFSETS = 800000;
constexpr size_t WS_CURSORS = 1600000;
constexpr size_t WS_BSUMS   = 2400000;
constexpr size_t WS_BBASE   = 2401024;
constexpr size_t WS_ENTRIES = 2402048;
constexpr size_t WS_NEEDED  = WS_ENTRIES + (size_t)NINC * 8;

__global__ __launch_bounds__(256) void count_kernel(
        const int* __restrict__ faces, int* __restrict__ counts) {
    int f = blockIdx.x * blockDim.x + threadIdx.x;
    if (f >= NFACES) return;
    int base = (f / Fc) * Nc;
    atomicAdd(&counts[faces[3*f+0] + base], 1);
    atomicAdd(&counts[faces[3*f+1] + base], 1);
    atomicAdd(&counts[faces[3*f+2] + base], 1);
}

__global__ __launch_bounds__(256) void scanA(
        const int* __restrict__ counts, int* __restrict__ bsums) {
    __shared__ int s[256];
    int t = threadIdx.x, b = blockIdx.x;
    int idx = b * SCAN_ELEMS + t * 4;
    int v = 0;
    if (idx + 4 <= BN) {
        int4 c = *(const int4*)(counts + idx);
        v = c.x + c.y + c.z + c.w;
    }
    s[t] = v; __syncthreads();
    for (int o = 128; o > 0; o >>= 1) {
        if (t < o) s[t] += s[t + o];
        __syncthreads();
    }
    if (t == 0) bsums[b] = s[0];
}

__global__ __launch_bounds__(256) void scanB(
        const int* __restrict__ bsums, int* __restrict__ bbase) {
    __shared__ int s[256];
    int t = threadIdx.x;
    int x = (t < NSCAN) ? bsums[t] : 0;
    s[t] = x; __syncthreads();
    for (int o = 1; o < 256; o <<= 1) {
        int v = (t >= o) ? s[t - o] : 0;
        __syncthreads();
        s[t] += v;
        __syncthreads();
    }
    bbase[t] = s[t] - x;
}

__global__ __launch_bounds__(256) void scanC(
        const int* __restrict__ counts, const int* __restrict__ bbase,
        int* __restrict__ offsets) {
    __shared__ int s[256];
    int t = threadIdx.x, b = blockIdx.x;
    int idx = b * SCAN_ELEMS + t * 4;
    int4 c = make_int4(0, 0, 0, 0);
    bool ok = (idx + 4 <= BN);
    if (ok) c = *(const int4*)(counts + idx);
    int tsum = c.x + c.y + c.z + c.w;
    s[t] = tsum; __syncthreads();
    for (int o = 1; o < 256; o <<= 1) {
        int v = (t >= o) ? s[t - o] : 0;
        __syncthreads();
        s[t] += v;
        __syncthreads();
    }
    int tbase = bbase[b] + s[t] - tsum;
    if (ok) {
        int4 o4;
        o4.x = tbase;
        o4.y = tbase + c.x;
        o4.z = tbase + c.x + c.y;
        o4.w = tbase + c.x + c.y + c.z;
        *(int4*)(offsets + idx) = o4;
    }
}

__global__ __launch_bounds__(256) void fill_kernel(
        const int* __restrict__ faces,
        const int* __restrict__ offsets,
        int* __restrict__ cursors,
        int2* __restrict__ entries) {
    int f = blockIdx.x * blockDim.x + threadIdx.x;
    if (f >= NFACES) return;
    int base = (f / Fc) * Nc;
    int v0 = faces[3*f+0] + base;
    int v1 = faces[3*f+1] + base;
    int v2 = faces[3*f+2] + base;
    int p0 = offsets[v0] + atomicAdd(&cursors[v0], 1);
    entries[p0] = make_int2(v1, v2);
    int p1 = offsets[v1] + atomicAdd(&cursors[v1], 1);
    entries[p1] = make_int2(v0, v2);
    int p2 = offsets[v2] + atomicAdd(&cursors[v2], 1);
    entries[p2] = make_int2(v0, v1);
}

__global__ __launch_bounds__(256) void gather_kernel(
        const float* __restrict__ verts,
        const int* __restrict__ counts,
        const int* __restrict__ offsets,
        const int2* __restrict__ entries,
        float* __restrict__ out) {
    int v    = (int)((blockIdx.x * blockDim.x + threadIdx.x) >> 6);
    int lane = threadIdx.x & 63;
    if (v >= BN) return;
    int c = counts[v];
    const int2* e = entries + offsets[v];
    float acc = 0.f;
    int i = 0;
    for (; i + 2 <= c; i += 2) {
        int2 a = e[i];
        int2 b = e[i + 1];
        acc += verts[(long)a.x * Dc + lane] + verts[(long)a.y * Dc + lane]
             + verts[(long)b.x * Dc + lane] + verts[(long)b.y * Dc + lane];
    }
    if (i < c) {
        int2 a = e[i];
        acc += verts[(long)a.x * Dc + lane] + verts[(long)a.y * Dc + lane];
    }
    float deg = 2.0f * (float)c;
    float own = verts[(long)v * Dc + lane];
    out[(long)v * Dc + lane] = (deg * own - acc) / (deg + 1e-12f);
}

extern "C" void kernel_launch(void* const* d_in, const int* in_sizes, int n_in,
                              void* d_out, int out_size, void* d_ws, size_t ws_size,
                              hipStream_t stream) {
    const float* verts = (const float*)d_in[0];
    const int*   faces = (const int*)d_in[1];   // int32 (JAX x64 disabled)
    float* out = (float*)d_out;
    char*  ws  = (char*)d_ws;

    if (ws_size >= A3_NEED) {
        // ---- Tier A3: binned build + fused LDS bucket-gather ----
        __half*       vh      = (__half*)(ws + A_VH);
        uint2*        entries = (uint2*)(ws + A_ENT);
        int*          bincur  = (int*)(ws + A_BCUR);

        hipMemsetAsync(bincur, 0, (size_t)NBINS * 32 * sizeof(int), stream);
        bin_conv<<<BINB + CONVB + 1, 256, 0, stream>>>(verts, faces, vh, bincur, entries);
        bucket_gather<<<NBINS8 * 2, 256, 0, stream>>>(vh, entries, bincur, out);
    } else if (ws_size >= B_NEED) {
        // ---- Tier B: round-4 direct record fill ----
        __half*       vh  = (__half*)(ws + B_VH);
        unsigned int* rec = (unsigned int*)(ws + B_REC);
        hipMemsetAsync(rec, 0, (size_t)BN * 32 * sizeof(unsigned int), stream);
        conv_fill<<<FILLB + CONVB, 256, 0, stream>>>(verts, faces, vh, rec);
        gather2<<<BN * 32 / 256, 256, 0, stream>>>(verts, vh, rec, out);
    } else if (ws_size >= WS_NEEDED) {
        // ---- Tier C: CSR f32 ----
        int*  counts  = (int*)(ws + WS_COUNTS);
        int*  offsets = (int*)(ws + WS_OFFSETS);
        int*  cursors = (int*)(ws + WS_CURSORS);
        int*  bsums   = (int*)(ws + WS_BSUMS);
        int*  bbase   = (int*)(ws + WS_BBASE);
        int2* entries = (int2*)(ws + WS_ENTRIES);

        hipMemsetAsync(counts,  0, (size_t)BN * sizeof(int), stream);
        hipMemsetAsync(cursors, 0, (size_t)BN * sizeof(int), stream);
        int fb = (NFACES + 255) / 256;
        count_kernel<<<fb, 256, 0, stream>>>(faces, counts);
        scanA<<<NSCAN, 256, 0, stream>>>(counts, bsums);
        scanB<<<1, 256, 0, stream>>>(bsums, bbase);
        scanC<<<NSCAN, 256, 0, stream>>>(counts, bbase, offsets);
        fill_kernel<<<fb, 256, 0, stream>>>(faces, offsets, cursors, entries);
        int gb = (BN * 64 + 255) / 256;
        gather_kernel<<<gb, 256, 0, stream>>>(verts, counts, offsets, entries, out);
    }
}